// Round 1
// baseline (808.806 us; speedup 1.0000x reference)
//
#include <hip/hip_runtime.h>

#define N_NODES 50000
#define FDIM 128
#define BN_EPS 1e-5f
#define SCAN_CHUNK 2048

// ---------------- edge dtype detector ----------------
// If edge_index arrives as raw int64 (little-endian, values < 2^31), every odd
// 32-bit word is 0. For int32 data the odd words are real indices (all-zero is
// impossible for 256 random values in [0,50000)).
__global__ void k_detect64(const int* __restrict__ e, int* __restrict__ flag) {
    __shared__ int snz[256];
    int i = threadIdx.x;
    snz[i] = e[2 * i + 1];
    __syncthreads();
    if (i == 0) {
        int nz = 0;
        for (int j = 0; j < 256; ++j) nz |= snz[j];
        *flag = (nz == 0) ? 1 : 0;
    }
}

__device__ __forceinline__ int edge_at(const int* e32, const long long* e64, int is64, long long idx) {
    return is64 ? (int)e64[idx] : e32[idx];
}

// ---------------- CSR build ----------------
__global__ void k_deg_count(const int* __restrict__ e, const int* __restrict__ flag,
                            int* __restrict__ cnt, int E) {
    int is64 = *flag;
    const long long* e64 = (const long long*)e;
    int i = blockIdx.x * blockDim.x + threadIdx.x;
    int stride = gridDim.x * blockDim.x;
    for (; i < E; i += stride) {
        int d = edge_at(e, e64, is64, (long long)E + i);  // dst row
        atomicAdd(&cnt[d], 1);
    }
}

__global__ void k_dinv(const int* __restrict__ cnt, float* __restrict__ dinv, int n) {
    int i = blockIdx.x * blockDim.x + threadIdx.x;
    if (i < n) dinv[i] = rsqrtf((float)(cnt[i] + 1));  // +1 self loop, deg>=1 always
}

__global__ void k_chunk_sum(const int* __restrict__ cnt, int* __restrict__ bsum, int n) {
    __shared__ int sb[256];
    int base = blockIdx.x * SCAN_CHUNK;
    int s = 0;
    for (int j = threadIdx.x; j < SCAN_CHUNK; j += 256) {
        int i = base + j;
        if (i < n) s += cnt[i];
    }
    sb[threadIdx.x] = s;
    __syncthreads();
    for (int off = 128; off > 0; off >>= 1) {
        if (threadIdx.x < off) sb[threadIdx.x] += sb[threadIdx.x + off];
        __syncthreads();
    }
    if (threadIdx.x == 0) bsum[blockIdx.x] = sb[0];
}

__global__ void k_scan_sums(const int* __restrict__ bsum, int* __restrict__ boff,
                            int* __restrict__ row_ptr, int nchunks, int n) {
    if (threadIdx.x == 0 && blockIdx.x == 0) {
        int run = 0;
        for (int b = 0; b < nchunks; ++b) { boff[b] = run; run += bsum[b]; }
        row_ptr[n] = run;  // == E
    }
}

__global__ void k_local_scan(const int* __restrict__ cnt, const int* __restrict__ boff,
                             int* __restrict__ row_ptr, int* __restrict__ cursor, int n) {
    __shared__ int sb[256];
    int tid = threadIdx.x;
    int base = blockIdx.x * SCAN_CHUNK + tid * 8;
    int v[8];
    int ts = 0;
#pragma unroll
    for (int j = 0; j < 8; ++j) {
        int i = base + j;
        v[j] = (i < n) ? cnt[i] : 0;
        ts += v[j];
    }
    sb[tid] = ts;
    __syncthreads();
    for (int off = 1; off < 256; off <<= 1) {
        int t = (tid >= off) ? sb[tid - off] : 0;
        __syncthreads();
        sb[tid] += t;
        __syncthreads();
    }
    int excl = sb[tid] - ts + boff[blockIdx.x];
#pragma unroll
    for (int j = 0; j < 8; ++j) {
        int i = base + j;
        if (i < n) { row_ptr[i] = excl; cursor[i] = excl; }
        excl += v[j];
    }
}

__global__ void k_fill(const int* __restrict__ e, const int* __restrict__ flag,
                       const float* __restrict__ dinv, int* __restrict__ cursor,
                       int* __restrict__ csrc, float* __restrict__ cw, int E) {
    int is64 = *flag;
    const long long* e64 = (const long long*)e;
    int i = blockIdx.x * blockDim.x + threadIdx.x;
    int stride = gridDim.x * blockDim.x;
    for (; i < E; i += stride) {
        int s = edge_at(e, e64, is64, i);
        int d = edge_at(e, e64, is64, (long long)E + i);
        int pos = atomicAdd(&cursor[d], 1);
        csrc[pos] = s;
        cw[pos] = dinv[s] * dinv[d];
    }
}

// ---------------- GEMM: out[n x 128] = h[n x 128] @ W[128 x 128] ----------------
// MODE bit0: accumulate into existing out. bit1: relu at store. bias nullable (MODE==0 path).
template <int MODE>
__global__ __launch_bounds__(256, 2) void k_gemm128(const float* __restrict__ h,
                                                    const float* __restrict__ W,
                                                    const float* __restrict__ bias,
                                                    float* __restrict__ out, int n) {
    __shared__ float sW[128 * 128];   // 64 KB
    __shared__ float sH[16 * 128];    // 8 KB
    int tid = threadIdx.x;
    {
        const float4* W4 = (const float4*)W;
        float4* sW4 = (float4*)sW;
        for (int i = tid; i < 128 * 128 / 4; i += 256) sW4[i] = W4[i];
    }
    int w = tid >> 6, l = tid & 63;
    float2 bv = make_float2(0.f, 0.f);
    if (bias) { bv.x = bias[2 * l]; bv.y = bias[2 * l + 1]; }
    int ntiles = (n + 15) >> 4;
    const float4* h4 = (const float4*)h;
    float4* sH4 = (float4*)sH;
    for (int tile = blockIdx.x; tile < ntiles; tile += gridDim.x) {
        __syncthreads();
        for (int i = tid; i < 16 * 32; i += 256) {
            int r = tile * 16 + (i >> 5);
            sH4[i] = (r < n) ? h4[r * 32 + (i & 31)] : make_float4(0, 0, 0, 0);
        }
        __syncthreads();
        float2 a0 = bv, a1 = bv, a2 = bv, a3 = bv;
        const float* hr = &sH[(w * 4) * 128];
#pragma unroll 4
        for (int k = 0; k < 128; ++k) {
            float2 wv = *(const float2*)&sW[k * 128 + 2 * l];
            float h0 = hr[k], h1 = hr[128 + k], h2 = hr[256 + k], h3 = hr[384 + k];
            a0.x = fmaf(h0, wv.x, a0.x); a0.y = fmaf(h0, wv.y, a0.y);
            a1.x = fmaf(h1, wv.x, a1.x); a1.y = fmaf(h1, wv.y, a1.y);
            a2.x = fmaf(h2, wv.x, a2.x); a2.y = fmaf(h2, wv.y, a2.y);
            a3.x = fmaf(h3, wv.x, a3.x); a3.y = fmaf(h3, wv.y, a3.y);
        }
        float2 accs[4] = {a0, a1, a2, a3};
        int r0 = tile * 16 + w * 4;
        float2* o2 = (float2*)out;
#pragma unroll
        for (int j = 0; j < 4; ++j) {
            int r = r0 + j;
            if (r < n) {
                float2 v = accs[j];
                if (MODE & 1) {
                    float2 old = o2[r * 64 + l];
                    v.x += old.x; v.y += old.y;
                }
                if (MODE & 2) { v.x = fmaxf(v.x, 0.f); v.y = fmaxf(v.y, 0.f); }
                o2[r * 64 + l] = v;
            }
        }
    }
}

// ---------------- CSR-pull aggregation: out = b + selfloop + sum_e w*z[src] ----------------
__global__ void k_aggregate(const float* __restrict__ z, const int* __restrict__ row_ptr,
                            const int* __restrict__ csrc, const float* __restrict__ cw,
                            const float* __restrict__ dinv, const float* __restrict__ bias,
                            float* __restrict__ out, int n) {
    int node = blockIdx.x * 2 + (threadIdx.x >> 7);
    int f = threadIdx.x & 127;
    if (node >= n) return;
    float di = dinv[node];
    float acc = bias[f] + di * di * z[node * 128 + f];
    int e = row_ptr[node], e1 = row_ptr[node + 1];
    for (; e + 2 <= e1; e += 2) {
        int s0 = csrc[e], s1 = csrc[e + 1];
        float w0 = cw[e], w1 = cw[e + 1];
        acc = fmaf(w0, z[s0 * 128 + f], acc);
        acc = fmaf(w1, z[s1 * 128 + f], acc);
    }
    if (e < e1) acc = fmaf(cw[e], z[csrc[e] * 128 + f], acc);
    out[node * 128 + f] = acc;
}

// ---------------- relu in-place + per-feature sum/sumsq ----------------
__global__ void k_relu_stats(float* __restrict__ t, float* __restrict__ stats, int n) {
    int f = threadIdx.x;  // 128 threads
    float s = 0.f, q = 0.f;
    for (int r = blockIdx.x * 4; r < n; r += gridDim.x * 4) {
#pragma unroll
        for (int j = 0; j < 4; ++j) {
            int rr = r + j;
            if (rr < n) {
                float v = t[rr * 128 + f];
                v = fmaxf(v, 0.f);
                t[rr * 128 + f] = v;
                s += v;
                q = fmaf(v, v, q);
            }
        }
    }
    atomicAdd(&stats[f], s);
    atomicAdd(&stats[128 + f], q);
}

__global__ void k_bn_finalize(const float* __restrict__ stats, const float* __restrict__ g,
                              const float* __restrict__ be, float* __restrict__ ss, float invn) {
    int f = threadIdx.x;
    float m = stats[f] * invn;
    float v = stats[128 + f] * invn - m * m;  // biased var
    float sc = g[f] * rsqrtf(v + BN_EPS);
    ss[f] = sc;
    ss[128 + f] = fmaf(-m, sc, be[f]);
}

__global__ void k_bn_apply(const float* __restrict__ y, const float* __restrict__ ss,
                           float* __restrict__ x, int n4) {
    int i = blockIdx.x * blockDim.x + threadIdx.x;
    int stride = gridDim.x * blockDim.x;
    const float4* y4 = (const float4*)y;
    float4* x4 = (float4*)x;
    const float4* sc4 = (const float4*)ss;
    const float4* sh4 = (const float4*)(ss + 128);
    for (; i < n4; i += stride) {
        int c = i & 31;
        float4 v = y4[i], a = sc4[c], b = sh4[c];
        float4 r;
        r.x = fmaf(v.x, a.x, b.x);
        r.y = fmaf(v.y, a.y, b.y);
        r.z = fmaf(v.z, a.z, b.z);
        r.w = fmaf(v.w, a.w, b.w);
        x4[i] = r;
    }
}

extern "C" void kernel_launch(void* const* d_in, const int* in_sizes, int n_in,
                              void* d_out, int out_size, void* d_ws, size_t ws_size,
                              hipStream_t stream) {
    const float* x   = (const float*)d_in[0];
    const int*   ei  = (const int*)d_in[1];
    const float* W1  = (const float*)d_in[3];
    const float* b1  = (const float*)d_in[4];
    const float* g1  = (const float*)d_in[5];
    const float* be1 = (const float*)d_in[6];
    const float* W2  = (const float*)d_in[7];
    const float* b2  = (const float*)d_in[8];
    const float* g2  = (const float*)d_in[9];
    const float* be2 = (const float*)d_in[10];
    const float* W3  = (const float*)d_in[11];
    const float* b3  = (const float*)d_in[12];
    const float* g3  = (const float*)d_in[13];
    const float* be3 = (const float*)d_in[14];
    const float* Wl  = (const float*)d_in[15];
    const float* bl  = (const float*)d_in[16];
    float* out = (float*)d_out;

    const int n = N_NODES;
    const int E = in_sizes[1] / 2;

    char* ws = (char*)d_ws;
    size_t off = 0;
    auto alloc = [&](size_t bytes) -> void* {
        void* p = ws + off;
        off += (bytes + 255) & ~((size_t)255);
        return p;
    };
    float* dinv    = (float*)alloc((size_t)n * 4);
    int*   cnt     = (int*)alloc((size_t)n * 4);
    int*   row_ptr = (int*)alloc((size_t)(n + 1) * 4);
    int*   cursor  = (int*)alloc((size_t)n * 4);
    int*   bsum    = (int*)alloc(64 * 4);
    int*   boff    = (int*)alloc(64 * 4);
    float* stats   = (float*)alloc(256 * 4);
    float* ss      = (float*)alloc(256 * 4);
    int*   flag    = (int*)alloc(256);
    int*   csrc    = (int*)alloc((size_t)E * 4);
    float* cw      = (float*)alloc((size_t)E * 4);
    float* z       = (float*)alloc((size_t)n * 128 * 4);
    float* t       = (float*)alloc((size_t)n * 128 * 4);
    float* x1      = (float*)alloc((size_t)n * 128 * 4);
    float* x2      = (float*)alloc((size_t)n * 128 * 4);
    float* x3      = (float*)alloc((size_t)n * 128 * 4);

    // ---- CSR build (per call; deterministic up to fp-sum order) ----
    hipMemsetAsync(cnt, 0, (size_t)n * 4, stream);
    k_detect64<<<1, 256, 0, stream>>>(ei, flag);
    k_deg_count<<<512, 256, 0, stream>>>(ei, flag, cnt, E);
    k_dinv<<<(n + 255) / 256, 256, 0, stream>>>(cnt, dinv, n);
    int nchunks = (n + SCAN_CHUNK - 1) / SCAN_CHUNK;
    k_chunk_sum<<<nchunks, 256, 0, stream>>>(cnt, bsum, n);
    k_scan_sums<<<1, 32, 0, stream>>>(bsum, boff, row_ptr, nchunks, n);
    k_local_scan<<<nchunks, 256, 0, stream>>>(cnt, boff, row_ptr, cursor, n);
    k_fill<<<512, 256, 0, stream>>>(ei, flag, dinv, cursor, csrc, cw, E);

    // ---- 3 GCN+BN layers ----
    auto layer = [&](const float* hin, const float* W, const float* b, const float* g,
                     const float* be, float* xout) {
        k_gemm128<0><<<512, 256, 0, stream>>>(hin, W, nullptr, z, n);
        k_aggregate<<<n / 2, 256, 0, stream>>>(z, row_ptr, csrc, cw, dinv, b, t, n);
        hipMemsetAsync(stats, 0, 256 * 4, stream);
        k_relu_stats<<<1024, 128, 0, stream>>>(t, stats, n);
        k_bn_finalize<<<1, 128, 0, stream>>>(stats, g, be, ss, 1.0f / n);
        k_bn_apply<<<2048, 256, 0, stream>>>(t, ss, xout, n * 32);
    };
    layer(x,  W1, b1, g1, be1, x1);
    layer(x1, W2, b2, g2, be2, x2);
    layer(x2, W3, b3, g3, be3, x3);

    // ---- final: out = relu([x1|x2|x3] @ Wl + bl) as 3 accumulating K=128 GEMMs ----
    k_gemm128<0><<<512, 256, 0, stream>>>(x1, Wl,              bl,      out, n);
    k_gemm128<1><<<512, 256, 0, stream>>>(x2, Wl + 128 * 128,  nullptr, out, n);
    k_gemm128<3><<<512, 256, 0, stream>>>(x3, Wl + 2 * 128 * 128, nullptr, out, n);
}

// Round 2
// 572.025 us; speedup vs baseline: 1.4139x; 1.4139x over previous
//
#include <hip/hip_runtime.h>

#define N_NODES 50000
#define BN_EPS 1e-5f
#define SCAN_CHUNK 2048

typedef __attribute__((ext_vector_type(8))) short short8;
typedef __attribute__((ext_vector_type(4))) float f32x4;

__device__ __forceinline__ unsigned short f2b(float x) {
    unsigned int u = __float_as_uint(x);
    unsigned int r = (u + 0x7fffu + ((u >> 16) & 1u)) >> 16;
    return (unsigned short)r;
}
__device__ __forceinline__ float b2f_lo(unsigned int u) { return __uint_as_float(u << 16); }
__device__ __forceinline__ float b2f_hi(unsigned int u) { return __uint_as_float(u & 0xffff0000u); }
__device__ __forceinline__ unsigned int pack2(float lo, float hi) {
    return (unsigned int)f2b(lo) | ((unsigned int)f2b(hi) << 16);
}

// ---------------- edge dtype detector ----------------
__global__ void k_detect64(const int* __restrict__ e, int* __restrict__ flag) {
    __shared__ int snz[256];
    int i = threadIdx.x;
    snz[i] = e[2 * i + 1];
    __syncthreads();
    if (i == 0) {
        int nz = 0;
        for (int j = 0; j < 256; ++j) nz |= snz[j];
        *flag = (nz == 0) ? 1 : 0;
    }
}

__device__ __forceinline__ int edge_at(const int* e32, const long long* e64, int is64, long long idx) {
    return is64 ? (int)e64[idx] : e32[idx];
}

// ---------------- CSR build ----------------
__global__ void k_deg_count(const int* __restrict__ e, const int* __restrict__ flag,
                            int* __restrict__ cnt, int E) {
    int is64 = *flag;
    const long long* e64 = (const long long*)e;
    int i = blockIdx.x * blockDim.x + threadIdx.x;
    int stride = gridDim.x * blockDim.x;
    for (; i < E; i += stride) {
        int d = edge_at(e, e64, is64, (long long)E + i);
        atomicAdd(&cnt[d], 1);
    }
}

__global__ void k_dinv(const int* __restrict__ cnt, float* __restrict__ dinv, int n) {
    int i = blockIdx.x * blockDim.x + threadIdx.x;
    if (i < n) dinv[i] = rsqrtf((float)(cnt[i] + 1));
}

__global__ void k_chunk_sum(const int* __restrict__ cnt, int* __restrict__ bsum, int n) {
    __shared__ int sb[256];
    int base = blockIdx.x * SCAN_CHUNK;
    int s = 0;
    for (int j = threadIdx.x; j < SCAN_CHUNK; j += 256) {
        int i = base + j;
        if (i < n) s += cnt[i];
    }
    sb[threadIdx.x] = s;
    __syncthreads();
    for (int off = 128; off > 0; off >>= 1) {
        if (threadIdx.x < off) sb[threadIdx.x] += sb[threadIdx.x + off];
        __syncthreads();
    }
    if (threadIdx.x == 0) bsum[blockIdx.x] = sb[0];
}

__global__ void k_scan_sums(const int* __restrict__ bsum, int* __restrict__ boff,
                            int* __restrict__ row_ptr, int nchunks, int n) {
    if (threadIdx.x == 0 && blockIdx.x == 0) {
        int run = 0;
        for (int b = 0; b < nchunks; ++b) { boff[b] = run; run += bsum[b]; }
        row_ptr[n] = run;
    }
}

__global__ void k_local_scan(const int* __restrict__ cnt, const int* __restrict__ boff,
                             int* __restrict__ row_ptr, int* __restrict__ cursor, int n) {
    __shared__ int sb[256];
    int tid = threadIdx.x;
    int base = blockIdx.x * SCAN_CHUNK + tid * 8;
    int v[8];
    int ts = 0;
#pragma unroll
    for (int j = 0; j < 8; ++j) {
        int i = base + j;
        v[j] = (i < n) ? cnt[i] : 0;
        ts += v[j];
    }
    sb[tid] = ts;
    __syncthreads();
    for (int off = 1; off < 256; off <<= 1) {
        int t = (tid >= off) ? sb[tid - off] : 0;
        __syncthreads();
        sb[tid] += t;
        __syncthreads();
    }
    int excl = sb[tid] - ts + boff[blockIdx.x];
#pragma unroll
    for (int j = 0; j < 8; ++j) {
        int i = base + j;
        if (i < n) { row_ptr[i] = excl; cursor[i] = excl; }
        excl += v[j];
    }
}

__global__ void k_fill(const int* __restrict__ e, const int* __restrict__ flag,
                       const float* __restrict__ dinv, int* __restrict__ cursor,
                       int* __restrict__ csrc, float* __restrict__ cw, int E) {
    int is64 = *flag;
    const long long* e64 = (const long long*)e;
    int i = blockIdx.x * blockDim.x + threadIdx.x;
    int stride = gridDim.x * blockDim.x;
    for (; i < E; i += stride) {
        int s = edge_at(e, e64, is64, i);
        int d = edge_at(e, e64, is64, (long long)E + i);
        int pos = atomicAdd(&cursor[d], 1);
        csrc[pos] = s;
        cw[pos] = dinv[s] * dinv[d];
    }
}

// ---------------- fp32 -> bf16 cast (x input) ----------------
__global__ void k_cast(const float* __restrict__ x, unsigned int* __restrict__ xb, int n32) {
    int i = blockIdx.x * blockDim.x + threadIdx.x;
    int stride = gridDim.x * blockDim.x;
    const float2* x2 = (const float2*)x;
    for (; i < n32; i += stride) {
        float2 v = x2[i];
        xb[i] = pack2(v.x, v.y);
    }
}

// ---------------- W prepack into MFMA B-fragment layout ----------------
// dst[job][ ((nt*4+kt)*64 + lane)*8 + j ] = bf16( W[rowoff + kt*32 + (lane>>4)*8 + j][nt*16 + (lane&15)] )
__global__ void k_prepack(const float* __restrict__ W1, const float* __restrict__ W2,
                          const float* __restrict__ W3, const float* __restrict__ Wl,
                          unsigned short* __restrict__ bp) {
    int job = blockIdx.x;
    const float* src;
    int rowoff = 0;
    if (job == 0) src = W1;
    else if (job == 1) src = W2;
    else if (job == 2) src = W3;
    else { src = Wl; rowoff = (job - 3) * 128; }
    unsigned short* dst = bp + job * 16384;
    for (int idx = threadIdx.x; idx < 16384; idx += 256) {
        int j = idx & 7, l = (idx >> 3) & 63, kt = (idx >> 9) & 3, nt = idx >> 11;
        int row = kt * 32 + (l >> 4) * 8 + j;
        int col = nt * 16 + (l & 15);
        dst[idx] = f2b(src[(rowoff + row) * 128 + col]);
    }
}

// ---------------- MFMA GEMM: out[n x 128] = A[n x 128(bf16, lda)] @ W ----------------
// MODE 0: store z bf16.  MODE 1: out fp32 = acc + bias.  MODE 2: out += acc.  MODE 3: out = relu(out + acc).
template <int MODE>
__global__ __launch_bounds__(256) void k_gemm_mfma(const unsigned short* __restrict__ A, int lda,
                                                   const unsigned short* __restrict__ Bp,
                                                   const float* __restrict__ bias,
                                                   void* __restrict__ outv, int n) {
    int tid = threadIdx.x;
    int l = tid & 63, w = tid >> 6;
    short8 breg[8][4];
    const short8* bp8 = (const short8*)Bp;
#pragma unroll
    for (int nt = 0; nt < 8; ++nt)
#pragma unroll
        for (int kt = 0; kt < 4; ++kt)
            breg[nt][kt] = bp8[(nt * 4 + kt) * 64 + l];
    int rit = l & 15;      // row in tile (A-frag)
    int kgrp = l >> 4;     // k-group
    int ntile = n >> 4;    // n divisible by 16
    int nwaves = gridDim.x * 4;
    for (int tile = blockIdx.x * 4 + w; tile < ntile; tile += nwaves) {
        int r0 = tile * 16;
        const unsigned short* arow = A + (size_t)(r0 + rit) * lda + kgrp * 8;
        f32x4 acc[8];
#pragma unroll
        for (int nt = 0; nt < 8; ++nt) acc[nt] = (f32x4)(0.f);
#pragma unroll
        for (int kt = 0; kt < 4; ++kt) {
            short8 af = *(const short8*)(arow + kt * 32);
#pragma unroll
            for (int nt = 0; nt < 8; ++nt)
                acc[nt] = __builtin_amdgcn_mfma_f32_16x16x32_bf16(af, breg[nt][kt], acc[nt], 0, 0, 0);
        }
        int crow0 = (l >> 4) * 4;
        int ccol = l & 15;
        if (MODE == 0) {
            unsigned short* z = (unsigned short*)outv;
#pragma unroll
            for (int nt = 0; nt < 8; ++nt) {
                int col = nt * 16 + ccol;
#pragma unroll
                for (int j = 0; j < 4; ++j)
                    z[(size_t)(r0 + crow0 + j) * 128 + col] = f2b(acc[nt][j]);
            }
        } else {
            float* o = (float*)outv;
#pragma unroll
            for (int nt = 0; nt < 8; ++nt) {
                int col = nt * 16 + ccol;
                float bv = (MODE == 1) ? bias[col] : 0.f;
#pragma unroll
                for (int j = 0; j < 4; ++j) {
                    size_t idx = (size_t)(r0 + crow0 + j) * 128 + col;
                    float v = acc[nt][j] + bv;
                    if (MODE >= 2) v += o[idx];
                    if (MODE == 3) v = fmaxf(v, 0.f);
                    o[idx] = v;
                }
            }
        }
    }
}

// ---------------- CSR-pull aggregate (bf16 z) + relu + BN stats, bf16 out ----------------
__global__ __launch_bounds__(256) void k_agg(const unsigned short* __restrict__ zb,
                                             const int* __restrict__ row_ptr,
                                             const int* __restrict__ csrc,
                                             const float* __restrict__ cw,
                                             const float* __restrict__ dinv,
                                             const float* __restrict__ bias,
                                             unsigned int* __restrict__ tb,
                                             float* __restrict__ stats, int n) {
    int tid = threadIdx.x;
    int l = tid & 63, w = tid >> 6;
    float b0 = bias[2 * l], b1 = bias[2 * l + 1];
    float s0 = 0.f, s1 = 0.f, q0 = 0.f, q1 = 0.f;
    int stride = gridDim.x * 4;
    for (int node = blockIdx.x * 4 + w; node < n; node += stride) {
        float di = dinv[node];
        unsigned int u = ((const unsigned int*)(zb + (size_t)node * 128))[l];
        float di2 = di * di;
        float acc0 = fmaf(di2, b2f_lo(u), b0);
        float acc1 = fmaf(di2, b2f_hi(u), b1);
        int e = row_ptr[node], e1 = row_ptr[node + 1];
        for (; e + 2 <= e1; e += 2) {
            int sA = csrc[e], sB = csrc[e + 1];
            float wA = cw[e], wB = cw[e + 1];
            unsigned int uA = ((const unsigned int*)(zb + (size_t)sA * 128))[l];
            unsigned int uB = ((const unsigned int*)(zb + (size_t)sB * 128))[l];
            acc0 = fmaf(wA, b2f_lo(uA), acc0);
            acc1 = fmaf(wA, b2f_hi(uA), acc1);
            acc0 = fmaf(wB, b2f_lo(uB), acc0);
            acc1 = fmaf(wB, b2f_hi(uB), acc1);
        }
        if (e < e1) {
            unsigned int uA = ((const unsigned int*)(zb + (size_t)csrc[e] * 128))[l];
            float wA = cw[e];
            acc0 = fmaf(wA, b2f_lo(uA), acc0);
            acc1 = fmaf(wA, b2f_hi(uA), acc1);
        }
        acc0 = fmaxf(acc0, 0.f);
        acc1 = fmaxf(acc1, 0.f);
        s0 += acc0; s1 += acc1;
        q0 = fmaf(acc0, acc0, q0); q1 = fmaf(acc1, acc1, q1);
        tb[(size_t)node * 64 + l] = pack2(acc0, acc1);
    }
    __shared__ float red[4][256];
    red[0][tid] = s0; red[1][tid] = s1; red[2][tid] = q0; red[3][tid] = q1;
    __syncthreads();
    int k = tid >> 6, li = tid & 63;
    float v = red[k][li] + red[k][64 + li] + red[k][128 + li] + red[k][192 + li];
    int f = 2 * li + (k & 1) + ((k >> 1) ? 128 : 0);
    atomicAdd(&stats[f], v);
}

__global__ void k_bn_finalize(const float* __restrict__ stats, const float* __restrict__ g,
                              const float* __restrict__ be, float* __restrict__ ss, float invn) {
    int f = threadIdx.x;
    float m = stats[f] * invn;
    float v = stats[128 + f] * invn - m * m;
    float sc = g[f] * rsqrtf(v + BN_EPS);
    ss[f] = sc;
    ss[128 + f] = fmaf(-m, sc, be[f]);
}

// read t (bf16x2), scale/shift, write into xcat column block (row stride 384 bf16 = 192 u32)
__global__ void k_bn_apply(const unsigned int* __restrict__ tb, const float* __restrict__ ss,
                           unsigned int* __restrict__ xcat, int n64, int coff) {
    int i = blockIdx.x * blockDim.x + threadIdx.x;
    int stride = gridDim.x * blockDim.x;
    for (; i < n64; i += stride) {
        int node = i >> 6, l = i & 63;
        unsigned int u = tb[i];
        int f0 = 2 * l, f1 = 2 * l + 1;
        float v0 = fmaf(b2f_lo(u), ss[f0], ss[128 + f0]);
        float v1 = fmaf(b2f_hi(u), ss[f1], ss[128 + f1]);
        xcat[(size_t)node * 192 + coff + l] = pack2(v0, v1);
    }
}

extern "C" void kernel_launch(void* const* d_in, const int* in_sizes, int n_in,
                              void* d_out, int out_size, void* d_ws, size_t ws_size,
                              hipStream_t stream) {
    const float* x   = (const float*)d_in[0];
    const int*   ei  = (const int*)d_in[1];
    const float* W1  = (const float*)d_in[3];
    const float* b1  = (const float*)d_in[4];
    const float* g1  = (const float*)d_in[5];
    const float* be1 = (const float*)d_in[6];
    const float* W2  = (const float*)d_in[7];
    const float* b2  = (const float*)d_in[8];
    const float* g2  = (const float*)d_in[9];
    const float* be2 = (const float*)d_in[10];
    const float* W3  = (const float*)d_in[11];
    const float* b3  = (const float*)d_in[12];
    const float* g3  = (const float*)d_in[13];
    const float* be3 = (const float*)d_in[14];
    const float* Wl  = (const float*)d_in[15];
    const float* bl  = (const float*)d_in[16];
    float* out = (float*)d_out;

    const int n = N_NODES;
    const int E = in_sizes[1] / 2;

    char* ws = (char*)d_ws;
    size_t off = 0;
    auto alloc = [&](size_t bytes) -> void* {
        void* p = ws + off;
        off += (bytes + 255) & ~((size_t)255);
        return p;
    };
    float*          dinv    = (float*)alloc((size_t)n * 4);
    int*            cnt     = (int*)alloc((size_t)n * 4);
    int*            row_ptr = (int*)alloc((size_t)(n + 1) * 4);
    int*            cursor  = (int*)alloc((size_t)n * 4);
    int*            bsum    = (int*)alloc(64 * 4);
    int*            boff    = (int*)alloc(64 * 4);
    float*          stats   = (float*)alloc(256 * 4);
    float*          ss      = (float*)alloc(256 * 4);
    int*            flag    = (int*)alloc(256);
    int*            csrc    = (int*)alloc((size_t)E * 4);
    float*          cw      = (float*)alloc((size_t)E * 4);
    unsigned short* bp      = (unsigned short*)alloc(6 * 16384 * 2);
    unsigned int*   xb      = (unsigned int*)alloc((size_t)n * 64 * 4);   // x as bf16
    unsigned short* zb      = (unsigned short*)alloc((size_t)n * 128 * 2);
    unsigned int*   tb      = (unsigned int*)alloc((size_t)n * 64 * 4);
    unsigned int*   xcat    = (unsigned int*)alloc((size_t)n * 192 * 4);  // [n][384] bf16

    // ---- CSR build ----
    hipMemsetAsync(cnt, 0, (size_t)n * 4, stream);
    k_detect64<<<1, 256, 0, stream>>>(ei, flag);
    k_deg_count<<<512, 256, 0, stream>>>(ei, flag, cnt, E);
    k_dinv<<<(n + 255) / 256, 256, 0, stream>>>(cnt, dinv, n);
    int nchunks = (n + SCAN_CHUNK - 1) / SCAN_CHUNK;
    k_chunk_sum<<<nchunks, 256, 0, stream>>>(cnt, bsum, n);
    k_scan_sums<<<1, 32, 0, stream>>>(bsum, boff, row_ptr, nchunks, n);
    k_local_scan<<<nchunks, 256, 0, stream>>>(cnt, boff, row_ptr, cursor, n);
    k_fill<<<512, 256, 0, stream>>>(ei, flag, dinv, cursor, csrc, cw, E);

    // ---- precompute ----
    k_cast<<<2048, 256, 0, stream>>>(x, xb, n * 64);
    k_prepack<<<6, 256, 0, stream>>>(W1, W2, W3, Wl, bp);

    // ---- 3 GCN+BN layers ----
    auto layer = [&](const unsigned short* Ain, int lda, const unsigned short* Bpk,
                     const float* b, const float* g, const float* be, int coff) {
        k_gemm_mfma<0><<<512, 256, 0, stream>>>(Ain, lda, Bpk, nullptr, zb, n);
        hipMemsetAsync(stats, 0, 256 * 4, stream);
        k_agg<<<1280, 256, 0, stream>>>(zb, row_ptr, csrc, cw, dinv, b, tb, stats, n);
        k_bn_finalize<<<1, 128, 0, stream>>>(stats, g, be, ss, 1.0f / n);
        k_bn_apply<<<2048, 256, 0, stream>>>(tb, ss, xcat, n * 64, coff);
    };
    const unsigned short* xc16 = (const unsigned short*)xcat;
    layer((const unsigned short*)xb, 128, bp,             b1, g1, be1, 0);
    layer(xc16,                      384, bp + 16384,     b2, g2, be2, 64);
    layer(xc16 + 128,                384, bp + 2 * 16384, b3, g3, be3, 128);

    // ---- final: out = relu([x1|x2|x3] @ Wl + bl) as 3 accumulating K=128 MFMA passes ----
    k_gemm_mfma<1><<<512, 256, 0, stream>>>(xc16,       384, bp + 3 * 16384, bl, out, n);
    k_gemm_mfma<2><<<512, 256, 0, stream>>>(xc16 + 128, 384, bp + 4 * 16384, nullptr, out, n);
    k_gemm_mfma<3><<<512, 256, 0, stream>>>(xc16 + 256, 384, bp + 5 * 16384, nullptr, out, n);
}